// Round 5
// baseline (116.921 us; speedup 1.0000x reference)
//
#include <hip/hip_runtime.h>

#define D_OUT 1024
#define BATCH 65536
#define NBLOCKS 2048

typedef float f32x4 __attribute__((ext_vector_type(4)));

__device__ __forceinline__ f32x4 affine4(f32x4 h, f32x4 w, f32x4 b) {
    f32x4 r;
#pragma unroll
    for (int i = 0; i < 4; ++i) r[i] = fmaf(h[i], w[i], b[i]);
    return r;
}

// Eigen/XLA rational tanh: tanh(x) ~= x*P(x^2)/Q(x^2), clamp |x|<=7.90531
// (err ~1e-7). The 4 divisions are amortized into ONE v_rcp_f32 via
// prefix/suffix products of the Q's (Q in [0.0049, 0.9]: product of 4 stays
// in [5.7e-10, 0.66] -> no overflow/denormals). Trans ops per 4 elems: 1
// (vs 8 for the exp-based form) -- this kernel was trans-issue-bound.
__device__ __forceinline__ f32x4 tanh4_pade(f32x4 v) {
    f32x4 p, q;
#pragma unroll
    for (int i = 0; i < 4; ++i) {
        float xi = fminf(fmaxf(v[i], -7.90531110f), 7.90531110f);
        float ri = xi * xi;
        float pi = fmaf(ri, 4.37031012579801e-16f, 2.00018790482477e-13f);
        pi = fmaf(ri, pi, -8.60467152213735e-11f);
        pi = fmaf(ri, pi, 5.12229709037114e-08f);
        pi = fmaf(ri, pi, 1.48572235717979e-05f);
        pi = fmaf(ri, pi, 6.37261928875436e-04f);
        pi = fmaf(ri, pi, 4.89352455891786e-03f);
        p[i] = pi * xi;
        float qi = fmaf(ri, 1.19825839466702e-06f, 1.18534705686654e-04f);
        qi = fmaf(ri, qi, 2.26843463243900e-03f);
        q[i] = fmaf(ri, qi, 4.89352518554385e-03f);
    }
    const float p01 = q[0] * q[1];
    const float p23 = q[2] * q[3];
    const float rall = __builtin_amdgcn_rcpf(p01 * p23);
    const float r01 = rall * p23;   // = 1/(q0*q1)
    const float r23 = rall * p01;   // = 1/(q2*q3)
    f32x4 out;
    out[0] = p[0] * (r01 * q[1]);
    out[1] = p[1] * (r01 * q[0]);
    out[2] = p[2] * (r23 * q[3]);
    out[3] = p[3] * (r23 * q[2]);
    return out;
}

__global__ __launch_bounds__(256, 4) void OneToOneDeepNet_kernel(
        const float* __restrict__ x,
        const float* __restrict__ W,
        const float* __restrict__ B,
        float* __restrict__ out) {
    const int col4 = threadIdx.x << 2;   // this thread's 4 columns

    // Per-channel params: 4 layers x (w,b) x f32x4 = 32 VGPRs, loaded once.
    const f32x4 w0 = *(const f32x4*)(W + 0 * D_OUT + col4);
    const f32x4 w1 = *(const f32x4*)(W + 1 * D_OUT + col4);
    const f32x4 w2 = *(const f32x4*)(W + 2 * D_OUT + col4);
    const f32x4 w3 = *(const f32x4*)(W + 3 * D_OUT + col4);
    const f32x4 b0 = *(const f32x4*)(B + 0 * D_OUT + col4);
    const f32x4 b1 = *(const f32x4*)(B + 1 * D_OUT + col4);
    const f32x4 b2 = *(const f32x4*)(B + 2 * D_OUT + col4);
    const f32x4 b3 = *(const f32x4*)(B + 3 * D_OUT + col4);

    // One block-iteration = one full row (256 threads * 4 cols = 1024).
    // This plain schedule was the best of R1-R4; only the tanh changed.
    for (int row = blockIdx.x; row < BATCH; row += NBLOCKS) {
        const size_t off = (size_t)row * D_OUT + col4;
        f32x4 h = *(const f32x4*)(x + off);
        h = tanh4_pade(affine4(h, w0, b0));
        h = tanh4_pade(affine4(h, w1, b1));
        h = tanh4_pade(affine4(h, w2, b2));
        h = affine4(h, w3, b3);
        *(f32x4*)(out + off) = h;
    }
}

extern "C" void kernel_launch(void* const* d_in, const int* in_sizes, int n_in,
                              void* d_out, int out_size, void* d_ws, size_t ws_size,
                              hipStream_t stream) {
    const float* x = (const float*)d_in[0];
    const float* W = (const float*)d_in[1];
    const float* B = (const float*)d_in[2];
    float* out = (float*)d_out;
    OneToOneDeepNet_kernel<<<NBLOCKS, 256, 0, stream>>>(x, W, B, out);
}

// Round 6
// 113.303 us; speedup vs baseline: 1.0319x; 1.0319x over previous
//
#include <hip/hip_runtime.h>

#define D_OUT 1024
#define BATCH 65536
#define NBLOCKS 2048
#define STRIDE (NBLOCKS * D_OUT)          // elements between a block's rows
#define NITER (BATCH / NBLOCKS)           // 32 rows per block

typedef float f32x4 __attribute__((ext_vector_type(4)));

// fast tanh: 1 - 2/(e^{2v}+1). No clamp needed:
//   v->+inf: e=inf, rcp=0 -> 1 ;  v->-inf: e=0, rcp(1)=1 -> -1. No NaN path.
__device__ __forceinline__ float ftanh(float v) {
    float e = __expf(2.0f * v);
    return fmaf(-2.0f, __builtin_amdgcn_rcpf(e + 1.0f), 1.0f);
}

__device__ __forceinline__ f32x4 affine4(f32x4 h, f32x4 w, f32x4 b) {
    f32x4 r;
#pragma unroll
    for (int i = 0; i < 4; ++i) r[i] = fmaf(h[i], w[i], b[i]);
    return r;
}

__device__ __forceinline__ f32x4 tanh4(f32x4 h) {
    f32x4 r;
#pragma unroll
    for (int i = 0; i < 4; ++i) r[i] = ftanh(h[i]);
    return r;
}

// Rolling 2-deep software pipeline: load for row i+2 is issued BEFORE the
// compute chain of row i, so every thread keeps 2x 16B loads in flight at all
// times (the ~300-cycle tanh chain never drains the memory pipe).
__global__ __launch_bounds__(256, 4) void OneToOneDeepNet_kernel(
        const float* __restrict__ x,
        const float* __restrict__ W,
        const float* __restrict__ B,
        float* __restrict__ out) {
    const int col4 = threadIdx.x << 2;   // this thread's 4 columns

    // Per-channel params: 4 layers x (w,b) x f32x4 = 32 VGPRs, loaded once.
    const f32x4 w0 = *(const f32x4*)(W + 0 * D_OUT + col4);
    const f32x4 w1 = *(const f32x4*)(W + 1 * D_OUT + col4);
    const f32x4 w2 = *(const f32x4*)(W + 2 * D_OUT + col4);
    const f32x4 w3 = *(const f32x4*)(W + 3 * D_OUT + col4);
    const f32x4 b0 = *(const f32x4*)(B + 0 * D_OUT + col4);
    const f32x4 b1 = *(const f32x4*)(B + 1 * D_OUT + col4);
    const f32x4 b2 = *(const f32x4*)(B + 2 * D_OUT + col4);
    const f32x4 b3 = *(const f32x4*)(B + 3 * D_OUT + col4);

    // u32 element offsets (max 67M) against uniform base pointers.
    unsigned off = (unsigned)blockIdx.x * D_OUT + col4;

    f32x4 cur = *(const f32x4*)(x + off);
    f32x4 nxt = *(const f32x4*)(x + off + STRIDE);

#pragma unroll 2
    for (int i = 0; i < NITER - 2; ++i) {
        f32x4 n2 = *(const f32x4*)(x + off + 2 * STRIDE);  // issue 2 ahead
        f32x4 h = cur;
        h = tanh4(affine4(h, w0, b0));
        h = tanh4(affine4(h, w1, b1));
        h = tanh4(affine4(h, w2, b2));
        h = affine4(h, w3, b3);
        *(f32x4*)(out + off) = h;
        cur = nxt;
        nxt = n2;
        off += STRIDE;
    }
    // Epilogue: last two rows (loads already in flight).
    {
        f32x4 h = cur;
        h = tanh4(affine4(h, w0, b0));
        h = tanh4(affine4(h, w1, b1));
        h = tanh4(affine4(h, w2, b2));
        h = affine4(h, w3, b3);
        *(f32x4*)(out + off) = h;
        off += STRIDE;
        h = nxt;
        h = tanh4(affine4(h, w0, b0));
        h = tanh4(affine4(h, w1, b1));
        h = tanh4(affine4(h, w2, b2));
        h = affine4(h, w3, b3);
        *(f32x4*)(out + off) = h;
    }
}

extern "C" void kernel_launch(void* const* d_in, const int* in_sizes, int n_in,
                              void* d_out, int out_size, void* d_ws, size_t ws_size,
                              hipStream_t stream) {
    const float* x = (const float*)d_in[0];
    const float* W = (const float*)d_in[1];
    const float* B = (const float*)d_in[2];
    float* out = (float*)d_out;
    OneToOneDeepNet_kernel<<<NBLOCKS, 256, 0, stream>>>(x, W, B, out);
}

// Round 7
// 110.684 us; speedup vs baseline: 1.0563x; 1.0237x over previous
//
#include <hip/hip_runtime.h>

#define D_OUT 1024
#define BATCH 65536
#define NBLOCKS 2048

// fast tanh: (e^{2v}-1)/(e^{2v}+1) with hardware exp + rcp.
// clamp to +-9 so e^{2v} stays finite (e^18 ~ 6.6e7); rel err ~1e-6.
__device__ __forceinline__ float ftanh(float v) {
    v = fminf(fmaxf(v, -9.0f), 9.0f);
    float e = __expf(2.0f * v);
    return (e - 1.0f) * __builtin_amdgcn_rcpf(e + 1.0f);
}

__device__ __forceinline__ float4 affine4(float4 h, float4 w, float4 b) {
    float4 r;
    r.x = fmaf(h.x, w.x, b.x);
    r.y = fmaf(h.y, w.y, b.y);
    r.z = fmaf(h.z, w.z, b.z);
    r.w = fmaf(h.w, w.w, b.w);
    return r;
}

__device__ __forceinline__ float4 tanh4(float4 h) {
    float4 r;
    r.x = ftanh(h.x);
    r.y = ftanh(h.y);
    r.z = ftanh(h.z);
    r.w = ftanh(h.w);
    return r;
}

// Best-of-session schedule (R1): plain per-row grid-stride loop, 4 waves/EU.
// Measured 109.6 us = 4.90 TB/s effective = the real-op streaming ceiling
// (matches learn_hip m146 RMSNorm 4.89 TB/s). Deeper MLP, higher occupancy,
// NT hints, and cheaper tanh were all neutral-to-negative (R3-R6).
__global__ __launch_bounds__(256, 4) void OneToOneDeepNet_kernel(
        const float* __restrict__ x,
        const float* __restrict__ W,
        const float* __restrict__ B,
        float* __restrict__ out) {
    const int t = threadIdx.x;      // 0..255
    const int col4 = t << 2;        // this thread's 4 columns

    // Per-channel params: 4 layers x (w,b) x float4 = 32 VGPRs, loaded once.
    const float4 w0 = *(const float4*)(W + 0 * D_OUT + col4);
    const float4 w1 = *(const float4*)(W + 1 * D_OUT + col4);
    const float4 w2 = *(const float4*)(W + 2 * D_OUT + col4);
    const float4 w3 = *(const float4*)(W + 3 * D_OUT + col4);
    const float4 b0 = *(const float4*)(B + 0 * D_OUT + col4);
    const float4 b1 = *(const float4*)(B + 1 * D_OUT + col4);
    const float4 b2 = *(const float4*)(B + 2 * D_OUT + col4);
    const float4 b3 = *(const float4*)(B + 3 * D_OUT + col4);

    // One block-iteration = one full row (256 threads * 4 cols = 1024).
    for (int row = blockIdx.x; row < BATCH; row += NBLOCKS) {
        const size_t off = (size_t)row * D_OUT + col4;
        float4 h = *(const float4*)(x + off);
        h = tanh4(affine4(h, w0, b0));
        h = tanh4(affine4(h, w1, b1));
        h = tanh4(affine4(h, w2, b2));
        h = affine4(h, w3, b3);
        *(float4*)(out + off) = h;
    }
}

extern "C" void kernel_launch(void* const* d_in, const int* in_sizes, int n_in,
                              void* d_out, int out_size, void* d_ws, size_t ws_size,
                              hipStream_t stream) {
    const float* x = (const float*)d_in[0];
    const float* W = (const float*)d_in[1];
    const float* B = (const float*)d_in[2];
    float* out = (float*)d_out;
    OneToOneDeepNet_kernel<<<NBLOCKS, 256, 0, stream>>>(x, W, B, out);
}